// Round 2
// baseline (75.765 us; speedup 1.0000x reference)
//
#include <hip/hip_runtime.h>

#define NROWS 8192
#define DDIM 64
#define HDIM 256
#define W1S 260   // LDS row stride (ushort) for W1 [64][260]: 520B/row, quad-step ≡16 banks -> free 2-way
#define W2S 68    // LDS row stride (ushort) for W2 [256][68]: 136B/row, quad-step ≡16 banks -> free 2-way
#define HPAD 264  // h row stride (ushort)

using bf16x8 = __attribute__((ext_vector_type(8))) short;
using f32x4  = __attribute__((ext_vector_type(4))) float;

__device__ __forceinline__ unsigned short f2bf(float x) {
    unsigned u = __float_as_uint(x);
    u += 0x7FFFu + ((u >> 16) & 1u);   // round-to-nearest-even
    return (unsigned short)(u >> 16);
}
__device__ __forceinline__ unsigned pack2(float a, float b) {
    return (unsigned)f2bf(a) | ((unsigned)f2bf(b) << 16);
}
__device__ __forceinline__ float fast_tanh(float x) {
    float e = __expf(2.0f * x);
    return 1.0f - 2.0f * __builtin_amdgcn_rcpf(e + 1.0f);
}

// One fused kernel: 16 rows/block, 256 threads (4 waves), 512 blocks, no ws.
__global__ __launch_bounds__(256)
void ode_fused(const float* __restrict__ t,
               const float* __restrict__ y,
               const float* __restrict__ W1,
               const float* __restrict__ b1,
               const float* __restrict__ wt,
               const float* __restrict__ W2,
               const float* __restrict__ b2,
               float* __restrict__ out) {
    const int tid  = threadIdx.x;
    const int w    = tid >> 6;     // wave 0..3
    const int lane = tid & 63;
    const int l16  = lane & 15;
    const int quad = lane >> 4;
    const int row0 = blockIdx.x * 16;

    __shared__ __align__(16) unsigned short w1s[64 * W1S];    // 33,280 B  (natural [k][m], bf16)
    __shared__ __align__(16) unsigned short w2s[256 * W2S];   // 34,816 B  (natural [m][n], bf16)
    __shared__ __align__(16) unsigned short h_lds[16 * HPAD]; //  8,448 B
    __shared__ float svs[HDIM];                               //  1,024 B
    __shared__ float dvp[64];                                 //    256 B   => ~76 KiB -> 2 blocks/CU

    // ---- stage W1 [64][256] fp32 -> LDS bf16 (coalesced float4 reads, aligned 8B LDS writes)
    const float4* W1v = (const float4*)W1;
    const float4* W2v = (const float4*)W2;
    #pragma unroll
    for (int i = 0; i < 16; ++i) {
        float4 f = W1v[i * 256 + tid];
        int p = (i * 256 + tid) * 4;                 // flat fp32 index
        unsigned* dst = (unsigned*)&w1s[(p >> 8) * W1S + (p & 255)];
        dst[0] = pack2(f.x, f.y); dst[1] = pack2(f.z, f.w);
    }
    // ---- stage W2 [256][64]
    #pragma unroll
    for (int i = 0; i < 16; ++i) {
        float4 f = W2v[i * 256 + tid];
        int p = (i * 256 + tid) * 4;
        unsigned* dst = (unsigned*)&w2s[(p >> 6) * W2S + (p & 63)];
        dst[0] = pack2(f.x, f.y); dst[1] = pack2(f.z, f.w);
    }
    // ---- Sv[m] = sum_k W1[k][m]*W2[m][k] in fp32 from global (L1/L2-hot after staging)
    {
        float s = 0.f;
        #pragma unroll
        for (int k = 0; k < DDIM; ++k) s += W1[k * HDIM + tid] * W2[tid * DDIM + k];
        svs[tid] = s;
    }

    // ---- A-frags from y (fp32 -> bf16). A[m=l16][k=quad*8+j]
    bf16x8 afr[2];
    const float* yrow = y + (size_t)(row0 + l16) * DDIM;
    #pragma unroll
    for (int ks = 0; ks < 2; ++ks) {
        float4 f0 = *(const float4*)(yrow + ks * 32 + quad * 8);
        float4 f1 = *(const float4*)(yrow + ks * 32 + quad * 8 + 4);
        bf16x8 a;
        a[0]=(short)f2bf(f0.x); a[1]=(short)f2bf(f0.y); a[2]=(short)f2bf(f0.z); a[3]=(short)f2bf(f0.w);
        a[4]=(short)f2bf(f1.x); a[5]=(short)f2bf(f1.y); a[6]=(short)f2bf(f1.z); a[7]=(short)f2bf(f1.w);
        afr[ks] = a;
    }

    // ---- hoist small epilogue params (hide latency behind the barrier)
    const float ts = t[0];
    float cbv[4];
    #pragma unroll
    for (int ct = 0; ct < 4; ++ct) {
        int m = w * 64 + ct * 16 + l16;
        cbv[ct] = b1[m] + ts * wt[m];
    }
    const int ncol = w * 16 + l16;
    const float b2v = b2[ncol];

    __syncthreads();

    // ---- phase 1: z = y @ W1 (wave w -> H cols [w*64, w*64+64), 4 col-tiles)
    f32x4 acc[4];
    #pragma unroll
    for (int ct = 0; ct < 4; ++ct) acc[ct] = (f32x4){0.f, 0.f, 0.f, 0.f};
    #pragma unroll
    for (int ct = 0; ct < 4; ++ct) {
        const int m = w * 64 + ct * 16 + l16;
        #pragma unroll
        for (int ks = 0; ks < 2; ++ks) {
            bf16x8 b;
            #pragma unroll
            for (int j = 0; j < 8; ++j)
                b[j] = (short)w1s[(ks * 32 + quad * 8 + j) * W1S + m];
            acc[ct] = __builtin_amdgcn_mfma_f32_16x16x32_bf16(afr[ks], b, acc[ct], 0, 0, 0);
        }
    }

    // ---- bias + tanh + divergence partials; h (bf16) -> LDS [row][m]
    float dv[4] = {0.f, 0.f, 0.f, 0.f};
    #pragma unroll
    for (int ct = 0; ct < 4; ++ct) {
        const int m = w * 64 + ct * 16 + l16;
        const float sv = svs[m];
        #pragma unroll
        for (int r = 0; r < 4; ++r) {            // C layout: col=l16, row=quad*4+r
            float z = acc[ct][r] + cbv[ct];
            float h = fast_tanh(z);
            dv[r] += (1.f - h * h) * sv;
            h_lds[(quad * 4 + r) * HPAD + m] = f2bf(h);
        }
    }
    #pragma unroll
    for (int off = 8; off; off >>= 1) {
        #pragma unroll
        for (int r = 0; r < 4; ++r) dv[r] += __shfl_down(dv[r], off, 16);
    }
    if (l16 == 0) {
        #pragma unroll
        for (int r = 0; r < 4; ++r) dvp[w * 16 + quad * 4 + r] = dv[r];
    }
    __syncthreads();

    // ---- phase 2: dy = h @ W2 (wave w -> output cols [w*16, w*16+16))
    f32x4 acc2 = (f32x4){0.f, 0.f, 0.f, 0.f};
    #pragma unroll
    for (int ks = 0; ks < 8; ++ks) {
        bf16x8 a = *(const bf16x8*)(&h_lds[l16 * HPAD + ks * 32 + quad * 8]);
        bf16x8 b;
        #pragma unroll
        for (int j = 0; j < 8; ++j)
            b[j] = (short)w2s[(ks * 32 + quad * 8 + j) * W2S + ncol];
        acc2 = __builtin_amdgcn_mfma_f32_16x16x32_bf16(a, b, acc2, 0, 0, 0);
    }
    #pragma unroll
    for (int r = 0; r < 4; ++r) {
        const int row = quad * 4 + r;
        out[(size_t)(row0 + row) * (DDIM + 1) + ncol] = acc2[r] + b2v;
    }

    // ---- divergence column (col 64)
    if (w == 0 && lane < 16) {
        float s = dvp[lane] + dvp[16 + lane] + dvp[32 + lane] + dvp[48 + lane];
        out[(size_t)(row0 + lane) * (DDIM + 1) + DDIM] = -s;
    }
}

extern "C" void kernel_launch(void* const* d_in, const int* in_sizes, int n_in,
                              void* d_out, int out_size, void* d_ws, size_t ws_size,
                              hipStream_t stream) {
    const float* t  = (const float*)d_in[0];
    const float* y  = (const float*)d_in[1];
    const float* W1 = (const float*)d_in[2];
    const float* b1 = (const float*)d_in[3];
    const float* wt = (const float*)d_in[4];
    const float* W2 = (const float*)d_in[5];
    const float* b2 = (const float*)d_in[6];
    float* out = (float*)d_out;

    ode_fused<<<NROWS / 16, 256, 0, stream>>>(t, y, W1, b1, wt, W2, b2, out);
}